// Round 1
// baseline (557.405 us; speedup 1.0000x reference)
//
#include <hip/hip_runtime.h>

#define IN_DIM  1024
#define OUT_DIM 4096
#define M_DIM   16384
#define QMAXF   127.0f

typedef int v4i __attribute__((ext_vector_type(4)));

// ---------------- column max of |in| over rows → atomicMax(bits) ----------------
__global__ void colmax_kernel(const float* __restrict__ in, unsigned* __restrict__ outb,
                              int rows, int cols, int rpb) {
    int j  = blockIdx.x * blockDim.x + threadIdx.x;   // column
    int r0 = blockIdx.y * rpb;
    int r1 = r0 + rpb; if (r1 > rows) r1 = rows;
    float m = 0.f;
    for (int r = r0; r < r1; ++r)
        m = fmaxf(m, fabsf(in[(size_t)r * cols + j]));
    atomicMax(&outb[j], __float_as_uint(m));          // nonneg floats: bit order == value order
}

// ---------------- scale[j] = act^0.5 / w^0.5 ; amax_w, amax_x via monotonicity ----------------
__global__ void scale_amax_kernel(float* __restrict__ wsf) {
    int j = threadIdx.x;                 // 0..1023, one block of 1024
    float wsc = wsf[j];                  // w_scale
    float asc = wsf[1024 + j];           // act_scale
    float s = sqrtf(asc) / sqrtf(wsc);
    if (s == 0.0f) s = 1.0f;
    wsf[2048 + j] = s;
    float aw = wsc * s;                  // max_i fl(|w_ij|*s_j) == fl(w_scale_j*s_j)
    float ax = asc / s;                  // max_i fl(|x_ij|/s_j) == fl(act_scale_j/s_j)
    int lane = j & 63, wid = j >> 6;
    #pragma unroll
    for (int off = 32; off; off >>= 1) {
        aw = fmaxf(aw, __shfl_down(aw, off));
        ax = fmaxf(ax, __shfl_down(ax, off));
    }
    __shared__ float rw[16], rx[16];
    if (lane == 0) { rw[wid] = aw; rx[wid] = ax; }
    __syncthreads();
    if (j == 0) {
        float mw = rw[0], mx = rx[0];
        #pragma unroll
        for (int i = 1; i < 16; ++i) { mw = fmaxf(mw, rw[i]); mx = fmaxf(mx, rx[i]); }
        wsf[3072] = mw;
        wsf[3073] = mx;
    }
}

// ---------------- quantize to int8: q = clip(rint((div? v/s_j : v*s_j)/qs), ±127) ----------------
__global__ void quant_kernel(const float4* __restrict__ in, const float* __restrict__ scale,
                             const float* __restrict__ amaxp, unsigned* __restrict__ out8,
                             int n4, int div) {
    float amax = *amaxp;
    float qs = amax > 0.f ? amax / QMAXF : 1.0f;
    int stride = gridDim.x * blockDim.x;
    for (int i = blockIdx.x * blockDim.x + threadIdx.x; i < n4; i += stride) {
        float4 v = in[i];
        int j = (i << 2) & (IN_DIM - 1);
        float s0 = scale[j], s1 = scale[j + 1], s2 = scale[j + 2], s3 = scale[j + 3];
        float t0, t1, t2, t3;
        if (div) { t0 = v.x / s0; t1 = v.y / s1; t2 = v.z / s2; t3 = v.w / s3; }
        else     { t0 = v.x * s0; t1 = v.y * s1; t2 = v.z * s2; t3 = v.w * s3; }
        int q0 = (int)fminf(fmaxf(rintf(t0 / qs), -QMAXF), QMAXF);
        int q1 = (int)fminf(fmaxf(rintf(t1 / qs), -QMAXF), QMAXF);
        int q2 = (int)fminf(fmaxf(rintf(t2 / qs), -QMAXF), QMAXF);
        int q3 = (int)fminf(fmaxf(rintf(t3 / qs), -QMAXF), QMAXF);
        out8[i] = (q0 & 0xff) | ((q1 & 0xff) << 8) | ((q2 & 0xff) << 16) | ((q3 & 0xff) << 24);
    }
}

// ---------------- int8 GEMM: out[M,N] = sp * (X8 @ W8^T) + bias ----------------
#define BM 128
#define BN 128
#define BK 128

__device__ __forceinline__ void load_lds16(const void* g, void* l) {
    __builtin_amdgcn_global_load_lds((const __attribute__((address_space(1))) void*)g,
                                     (__attribute__((address_space(3))) void*)l, 16, 0, 0);
}

__global__ __launch_bounds__(256) void gemm_i8_kernel(
    const char* __restrict__ Xq, const char* __restrict__ Wq,
    const float* __restrict__ bias, const float* __restrict__ wsf,
    float* __restrict__ out) {
    __shared__ char As[BM * BK];   // 16 KB
    __shared__ char Bs[BN * BK];   // 16 KB
    const int K = IN_DIM, N = OUT_DIM;
    int tid  = threadIdx.x;
    int lane = tid & 63, w = tid >> 6;
    int bn0 = blockIdx.x * BN, bm0 = blockIdx.y * BM;
    int wrow = (w >> 1) * 64, wcol = (w & 1) * 64;
    int l15 = lane & 15, l4 = lane >> 4;
    int swz = (lane & 7) << 4;     // (row&7)<<4 with row = 16*frag + l15  →  row&7 == lane&7

    v4i acc[4][4];
    #pragma unroll
    for (int i = 0; i < 4; ++i)
        #pragma unroll
        for (int jj = 0; jj < 4; ++jj)
            acc[i][jj] = (v4i){0, 0, 0, 0};

    for (int kt = 0; kt < K / BK; ++kt) {
        int k0 = kt * BK;
        // ---- stage A,B tiles: 16 KB each, 1024 chunks of 16B; XOR-swizzled SOURCE, linear dest ----
        #pragma unroll
        for (int q = 0; q < 4; ++q) {
            int c = q * 256 + w * 64 + lane;
            int row = c >> 3, slot = c & 7;
            int col = (slot * 16) ^ ((row & 7) << 4);
            load_lds16(Xq + (size_t)(bm0 + row) * K + k0 + col, As + q * 4096 + w * 1024);
            load_lds16(Wq + (size_t)(bn0 + row) * K + k0 + col, Bs + q * 4096 + w * 1024);
        }
        __syncthreads();   // compiler drains vmcnt(0) before barrier
        // ---- compute: 2 k-substeps of K=64, 16 MFMA each ----
        #pragma unroll
        for (int kk = 0; kk < 2; ++kk) {
            int coff = ((kk << 6) | (l4 << 4)) ^ swz;
            v4i a[4], b[4];
            #pragma unroll
            for (int am = 0; am < 4; ++am)
                a[am] = *(const v4i*)(As + (wrow + am * 16 + l15) * BK + coff);
            #pragma unroll
            for (int bb = 0; bb < 4; ++bb)
                b[bb] = *(const v4i*)(Bs + (wcol + bb * 16 + l15) * BK + coff);
            #pragma unroll
            for (int am = 0; am < 4; ++am)
                #pragma unroll
                for (int bb = 0; bb < 4; ++bb)
                    acc[am][bb] = __builtin_amdgcn_mfma_i32_16x16x64_i8(a[am], b[bb], acc[am][bb], 0, 0, 0);
        }
        __syncthreads();
    }

    float amw = wsf[3072], amx = wsf[3073];
    float sw = amw > 0.f ? amw / QMAXF : 1.0f;
    float sx = amx > 0.f ? amx / QMAXF : 1.0f;
    float sp = sw * sx;

    #pragma unroll
    for (int am = 0; am < 4; ++am) {
        int row = bm0 + wrow + am * 16 + l4 * 4;
        #pragma unroll
        for (int bb = 0; bb < 4; ++bb) {
            int col = bn0 + wcol + bb * 16 + l15;
            float bv = bias[col];
            #pragma unroll
            for (int r = 0; r < 4; ++r)
                out[(size_t)(row + r) * N + col] = fmaf(sp, (float)acc[am][bb][r], bv);
        }
    }
}

// ---------------- host ----------------
extern "C" void kernel_launch(void* const* d_in, const int* in_sizes, int n_in,
                              void* d_out, int out_size, void* d_ws, size_t ws_size,
                              hipStream_t stream) {
    const float* x      = (const float*)d_in[0];   // [16384, 1024]
    const float* weight = (const float*)d_in[1];   // [4096, 1024]
    const float* bias   = (const float*)d_in[2];   // [4096]
    float* out = (float*)d_out;

    float*    wsf = (float*)d_ws;
    unsigned* wsu = (unsigned*)d_ws;
    char* X8 = (char*)d_ws + 16384;                      // 16 MB
    char* W8 = X8 + (size_t)M_DIM * IN_DIM;              // 4 MB

    // zero the reduction area (harness poisons ws with 0xAA)
    hipMemsetAsync(d_ws, 0, 16384, stream);

    // column maxes
    colmax_kernel<<<dim3(IN_DIM / 256, 16),  256, 0, stream>>>(weight, wsu,        OUT_DIM, IN_DIM, 256);
    colmax_kernel<<<dim3(IN_DIM / 256, 128), 256, 0, stream>>>(x,      wsu + 1024, M_DIM,   IN_DIM, 128);

    // per-channel scale + per-tensor amaxes
    scale_amax_kernel<<<1, 1024, 0, stream>>>(wsf);

    // quantize weight (mul by scale) and activations (div by scale)
    quant_kernel<<<1024, 256, 0, stream>>>((const float4*)weight, wsf + 2048, wsf + 3072,
                                           (unsigned*)W8, OUT_DIM * IN_DIM / 4, 0);
    quant_kernel<<<2048, 256, 0, stream>>>((const float4*)x, wsf + 2048, wsf + 3073,
                                           (unsigned*)X8, M_DIM * IN_DIM / 4, 1);

    // int8 GEMM + epilogue
    gemm_i8_kernel<<<dim3(OUT_DIM / BN, M_DIM / BM), 256, 0, stream>>>(X8, W8, bias, wsf, out);
}

// Round 3
// 462.076 us; speedup vs baseline: 1.2063x; 1.2063x over previous
//
#include <hip/hip_runtime.h>

#define IN_DIM  1024
#define OUT_DIM 4096
#define M_DIM   16384
#define QMAXF   127.0f

typedef int v4i __attribute__((ext_vector_type(4)));

// ---------------- column max of |in| over rows, float4-vectorized ----------------
// 256 threads/block, thread t owns cols 4t..4t+3; block reads whole 4KB rows.
__global__ void colmax4_kernel(const float4* __restrict__ in, unsigned* __restrict__ outb,
                               int rows, int rpb) {
    int t  = threadIdx.x;                       // 0..255
    int r0 = blockIdx.x * rpb;
    int r1 = r0 + rpb; if (r1 > rows) r1 = rows;
    float m0 = 0.f, m1 = 0.f, m2 = 0.f, m3 = 0.f;
    #pragma unroll 4
    for (int r = r0; r < r1; ++r) {
        float4 v = in[(size_t)r * 256 + t];
        m0 = fmaxf(m0, fabsf(v.x));
        m1 = fmaxf(m1, fabsf(v.y));
        m2 = fmaxf(m2, fabsf(v.z));
        m3 = fmaxf(m3, fabsf(v.w));
    }
    unsigned* o = outb + t * 4;
    atomicMax(o + 0, __float_as_uint(m0));      // nonneg floats: bit order == value order
    atomicMax(o + 1, __float_as_uint(m1));
    atomicMax(o + 2, __float_as_uint(m2));
    atomicMax(o + 3, __float_as_uint(m3));
}

// ---------------- scale[j] = act^0.5 / w^0.5 ; amax_w, amax_x via monotonicity ----------------
__global__ void scale_amax_kernel(float* __restrict__ wsf) {
    int j = threadIdx.x;                 // 0..1023
    float wsc = wsf[j];                  // w_scale
    float asc = wsf[1024 + j];           // act_scale
    float s = sqrtf(asc) / sqrtf(wsc);
    if (s == 0.0f) s = 1.0f;
    wsf[2048 + j] = s;
    float aw = wsc * s;                  // max_i fl(|w_ij|*s_j) == fl(w_scale_j*s_j)
    float ax = asc / s;                  // max_i fl(|x_ij|/s_j) == fl(act_scale_j/s_j)
    int lane = j & 63, wid = j >> 6;
    #pragma unroll
    for (int off = 32; off; off >>= 1) {
        aw = fmaxf(aw, __shfl_down(aw, off));
        ax = fmaxf(ax, __shfl_down(ax, off));
    }
    __shared__ float rw[16], rx[16];
    if (lane == 0) { rw[wid] = aw; rx[wid] = ax; }
    __syncthreads();
    if (j == 0) {
        float mw = rw[0], mx = rx[0];
        #pragma unroll
        for (int i = 1; i < 16; ++i) { mw = fmaxf(mw, rw[i]); mx = fmaxf(mx, rx[i]); }
        wsf[3072] = mw;
        wsf[3073] = mx;
    }
}

// ---------------- fused quantize W (mul scale) + X (div scale) to int8 ----------------
#define NW4 (OUT_DIM * IN_DIM / 4)   // 1,048,576 float4 chunks of W
#define NX4 (M_DIM * IN_DIM / 4)     // 4,194,304 float4 chunks of X

__device__ __forceinline__ unsigned pack_q4(float t0, float t1, float t2, float t3, float qs) {
    int q0 = (int)fminf(fmaxf(rintf(t0 / qs), -QMAXF), QMAXF);
    int q1 = (int)fminf(fmaxf(rintf(t1 / qs), -QMAXF), QMAXF);
    int q2 = (int)fminf(fmaxf(rintf(t2 / qs), -QMAXF), QMAXF);
    int q3 = (int)fminf(fmaxf(rintf(t3 / qs), -QMAXF), QMAXF);
    return (q0 & 0xff) | ((q1 & 0xff) << 8) | ((q2 & 0xff) << 16) | ((q3 & 0xff) << 24);
}

__global__ void quant_fused_kernel(const float4* __restrict__ w, const float4* __restrict__ x,
                                   const float* __restrict__ wsf,
                                   unsigned* __restrict__ w8, unsigned* __restrict__ x8) {
    const float4* scale4 = (const float4*)(wsf + 2048);
    float amw = wsf[3072], amx = wsf[3073];
    float qsw = amw > 0.f ? amw / QMAXF : 1.0f;
    float qsx = amx > 0.f ? amx / QMAXF : 1.0f;
    int stride = gridDim.x * blockDim.x;
    for (int i = blockIdx.x * blockDim.x + threadIdx.x; i < NW4 + NX4; i += stride) {
        if (i < NW4) {
            float4 v = w[i];
            float4 s = scale4[i & 255];
            w8[i] = pack_q4(v.x * s.x, v.y * s.y, v.z * s.z, v.w * s.w, qsw);
        } else {
            int k = i - NW4;
            float4 v = x[k];
            float4 s = scale4[k & 255];
            x8[k] = pack_q4(v.x / s.x, v.y / s.y, v.z / s.z, v.w / s.w, qsx);
        }
    }
}

// ---------------- int8 GEMM: out[M,N] = sp * (X8 @ W8^T) + bias ----------------
#define BM 128
#define BN 128
#define BK 128

__device__ __forceinline__ void load_lds16(const void* g, void* l) {
    __builtin_amdgcn_global_load_lds((const __attribute__((address_space(1))) void*)g,
                                     (__attribute__((address_space(3))) void*)l, 16, 0, 0);
}

__global__ __launch_bounds__(256) void gemm_i8_kernel(
    const char* __restrict__ Xq, const char* __restrict__ Wq,
    const float* __restrict__ bias, const float* __restrict__ wsf,
    float* __restrict__ out) {
    __shared__ char As[BM * BK];   // 16 KB
    __shared__ char Bs[BN * BK];   // 16 KB
    const int K = IN_DIM, N = OUT_DIM;
    int tid  = threadIdx.x;
    int lane = tid & 63, w = tid >> 6;

    // XCD-aware bijective swizzle (T1): nwg = 32*128 = 4096, 4096 % 8 == 0.
    int lin = blockIdx.y * gridDim.x + blockIdx.x;
    int swz = (lin & 7) * 512 + (lin >> 3);
    int bn0 = (swz & 31) * BN, bm0 = (swz >> 5) * BM;

    int wrow = (w >> 1) * 64, wcol = (w & 1) * 64;
    int l15 = lane & 15, l4 = lane >> 4;
    int swzl = (lane & 7) << 4;    // (row&7)<<4 with row = 16*frag + l15  →  row&7 == lane&7

    v4i acc[4][4];
    #pragma unroll
    for (int i = 0; i < 4; ++i)
        #pragma unroll
        for (int jj = 0; jj < 4; ++jj)
            acc[i][jj] = (v4i){0, 0, 0, 0};

    for (int kt = 0; kt < K / BK; ++kt) {
        int k0 = kt * BK;
        // ---- stage A,B tiles: 16 KB each; XOR-swizzled SOURCE, linear LDS dest ----
        #pragma unroll
        for (int q = 0; q < 4; ++q) {
            int c = q * 256 + w * 64 + lane;
            int row = c >> 3, slot = c & 7;
            int col = (slot * 16) ^ ((row & 7) << 4);
            load_lds16(Xq + (size_t)(bm0 + row) * K + k0 + col, As + q * 4096 + w * 1024);
            load_lds16(Wq + (size_t)(bn0 + row) * K + k0 + col, Bs + q * 4096 + w * 1024);
        }
        __syncthreads();   // compiler drains vmcnt(0) before barrier
        // ---- compute: 2 k-substeps of K=64, 16 MFMA each ----
        #pragma unroll
        for (int kk = 0; kk < 2; ++kk) {
            int coff = ((kk << 6) | (l4 << 4)) ^ swzl;
            v4i a[4], b[4];
            #pragma unroll
            for (int am = 0; am < 4; ++am)
                a[am] = *(const v4i*)(As + (wrow + am * 16 + l15) * BK + coff);
            #pragma unroll
            for (int bb = 0; bb < 4; ++bb)
                b[bb] = *(const v4i*)(Bs + (wcol + bb * 16 + l15) * BK + coff);
            #pragma unroll
            for (int am = 0; am < 4; ++am)
                #pragma unroll
                for (int bb = 0; bb < 4; ++bb)
                    acc[am][bb] = __builtin_amdgcn_mfma_i32_16x16x64_i8(a[am], b[bb], acc[am][bb], 0, 0, 0);
        }
        __syncthreads();
    }

    float amw = wsf[3072], amx = wsf[3073];
    float sw = amw > 0.f ? amw / QMAXF : 1.0f;
    float sx = amx > 0.f ? amx / QMAXF : 1.0f;
    float sp = sw * sx;

    #pragma unroll
    for (int am = 0; am < 4; ++am) {
        int row = bm0 + wrow + am * 16 + l4 * 4;
        #pragma unroll
        for (int bb = 0; bb < 4; ++bb) {
            int col = bn0 + wcol + bb * 16 + l15;
            float bv = bias[col];
            #pragma unroll
            for (int r = 0; r < 4; ++r)
                out[(size_t)(row + r) * N + col] = fmaf(sp, (float)acc[am][bb][r], bv);
        }
    }
}

// ---------------- host ----------------
extern "C" void kernel_launch(void* const* d_in, const int* in_sizes, int n_in,
                              void* d_out, int out_size, void* d_ws, size_t ws_size,
                              hipStream_t stream) {
    const float* x      = (const float*)d_in[0];   // [16384, 1024]
    const float* weight = (const float*)d_in[1];   // [4096, 1024]
    const float* bias   = (const float*)d_in[2];   // [4096]
    float* out = (float*)d_out;

    float*    wsf = (float*)d_ws;
    unsigned* wsu = (unsigned*)d_ws;
    char* X8 = (char*)d_ws + 16384;                      // 16 MB
    char* W8 = X8 + (size_t)M_DIM * IN_DIM;              // 4 MB

    // zero the reduction area (harness poisons ws with 0xAA)
    hipMemsetAsync(d_ws, 0, 16384, stream);

    // column maxes (float4: block covers all 1024 cols, reads full 4KB rows)
    colmax4_kernel<<<256, 256, 0, stream>>>((const float4*)weight, wsu,        OUT_DIM, 16);
    colmax4_kernel<<<256, 256, 0, stream>>>((const float4*)x,      wsu + 1024, M_DIM,   64);

    // per-channel scale + per-tensor amaxes
    scale_amax_kernel<<<1, 1024, 0, stream>>>(wsf);

    // fused quantize: W (mul by scale) then X (div by scale)
    quant_fused_kernel<<<2560, 256, 0, stream>>>((const float4*)weight, (const float4*)x,
                                                 wsf, (unsigned*)W8, (unsigned*)X8);

    // int8 GEMM + epilogue
    gemm_i8_kernel<<<dim3(OUT_DIM / BN, M_DIM / BM), 256, 0, stream>>>(X8, W8, bias, wsf, out);
}